// Round 15
// baseline (143.368 us; speedup 1.0000x reference)
//
#include <hip/hip_runtime.h>
#include <hip/hip_cooperative_groups.h>
#include <hip/hip_bf16.h>
#include <cstdint>
#include <cstddef>

namespace cg = cooperative_groups;

#define TOKENS 16384
#define DMODEL 4096
#define NEXP   64
#define NWAVE  8                      // waves per block = K-split within block
#define KSPAN  (DMODEL / NWAVE)       // 512 k per wave
#define NKC    (KSPAN / 16)           // 32 k16-chunks per wave
#define NMAC   (NKC / 2)              // 16 macro-iters (2 chunks = 128B/row burst)

typedef __attribute__((ext_vector_type(8)))  short bf16x8;   // 8 bf16 = 4 VGPRs
typedef __attribute__((ext_vector_type(16))) float f32x16;   // 32x32 acc

// 8 fp32 -> hi/lo bf16 fragments (RNE hi, exact fp32 residual -> lo; ~2^-17 rel)
__device__ __forceinline__ void cvt_hilo8(const float f[8], bf16x8* hi, bf16x8* lo) {
  union { __hip_bfloat16 b; unsigned short u; } cv;
  bf16x8 hv, lv;
#pragma unroll
  for (int j = 0; j < 8; ++j) {
    __hip_bfloat16 hb = __float2bfloat16(f[j]);
    cv.b = hb; hv[j] = (short)cv.u;
    float r = f[j] - __bfloat162float(hb);          // exact
    cv.b = __float2bfloat16(r); lv[j] = (short)cv.u;
  }
  *hi = hv; *lo = lv;
}

// ---------------- single cooperative kernel: W-prep phase + grid sync + GEMM/topk ------
// grid 256 x 512 thr, 1 block/CU (128KB LDS), co-resident by construction.
// Phase 1: blocks 0..63 convert W -> 32x32x16 bf16 hi/lo fragments (verified layout):
//   slot (kc*2+et)*64+l <- B[k=kc*16+(l>>5)*8+j][e=et*32+(l&31)] = W[e][k+j]
// Phase 2 (after grid.sync): R11 tile-pair GEMM + reduce + bias + top-2 + softmax.
__global__ __launch_bounds__(512, 2)
void router_all(const float* __restrict__ x, const float* __restrict__ W,
                uint4* __restrict__ wh, uint4* __restrict__ wl,
                const float* __restrict__ b, float* __restrict__ out) {
  __shared__ float red[NWAVE][64 * NEXP];   // 128 KB

  const int tid = threadIdx.x;

  // ---- phase 1: W fragment prep (32768 work items over first 64 blocks) ----
  {
    const int gidx = blockIdx.x * 512 + tid;
    if (gidx < 32768) {
      const int l  = gidx & 63;
      const int et = (gidx >> 6) & 1;
      const int kc = gidx >> 7;                      // 0..255 (global k16-chunk)
      const int e  = et * 32 + (l & 31);
      const int k  = kc * 16 + (l >> 5) * 8;
      const float* src = W + (size_t)e * DMODEL + k;
      float f[8];
#pragma unroll
      for (int j = 0; j < 8; ++j) f[j] = src[j];
      bf16x8 hi, lo;
      cvt_hilo8(f, &hi, &lo);
      const int slot = (kc * 2 + et) * 64 + l;
      wh[slot] = __builtin_bit_cast(uint4, hi);
      wl[slot] = __builtin_bit_cast(uint4, lo);
    }
  }
  __threadfence();                                   // device-scope visibility
  cg::this_grid().sync();

  // ---- phase 2: tile-pair GEMM (R11 body, verified) ----
  const int l   = tid & 63;
  const int w   = tid >> 6;                 // wave id = K-eighth
  const int t0  = blockIdx.x * 64;
  const int row = l & 31, g = l >> 5;

  const float* xpA = x + (size_t)(t0 + row) * DMODEL + w * KSPAN + g * 8;
  const float* xpB = xpA + (size_t)32 * DMODEL;
  const uint4* whp = wh + (size_t)w * (NKC * 128) + l;   // 128 uint4 per k16-chunk
  const uint4* wlp = wl + (size_t)w * (NKC * 128) + l;

  f32x16 accA0, accA1, accB0, accB1;
#pragma unroll
  for (int i = 0; i < 16; ++i) { accA0[i] = 0.f; accA1[i] = 0.f; accB0[i] = 0.f; accB1[i] = 0.f; }

  // x: macro (2 chunks x 2 tiles = 8 float4) double-buffered; W: depth-2 chunk rotation.
  float4 xa[2][8];
  uint4  ph0[2], ph1[2], pl0[2], pl1[2];

  auto ldxm = [&](int mac, int s) {          // 128B/row bursts
#pragma unroll
    for (int c = 0; c < 2; ++c) {
      const float* xn = xpA + (size_t)(mac * 2 + c) * 16;
      xa[s][c * 2]     = *(const float4*)(xn);
      xa[s][c * 2 + 1] = *(const float4*)(xn + 4);
    }
#pragma unroll
    for (int c = 0; c < 2; ++c) {
      const float* xn = xpB + (size_t)(mac * 2 + c) * 16;
      xa[s][4 + c * 2]     = *(const float4*)(xn);
      xa[s][4 + c * 2 + 1] = *(const float4*)(xn + 4);
    }
  };
  auto ldw = [&](int kc, int s) {
    ph0[s] = whp[(size_t)kc * 128];  ph1[s] = whp[(size_t)kc * 128 + 64];
    pl0[s] = wlp[(size_t)kc * 128];  pl1[s] = wlp[(size_t)kc * 128 + 64];
  };

  auto chunk = [&](int kc, int xs, int c) {  // one W chunk -> both tiles (12 MFMA)
    const int ws = kc & 1;
    float4 aA0 = xa[xs][c * 2],     aA1 = xa[xs][c * 2 + 1];
    float4 aB0 = xa[xs][4 + c * 2], aB1 = xa[xs][4 + c * 2 + 1];
    uint4 bh0 = ph0[ws], bh1 = ph1[ws], bl0 = pl0[ws], bl1 = pl1[ws];
    if (kc + 2 < NKC) ldw(kc + 2, ws);       // same parity -> same slot, freed this chunk
    float fA[8] = {aA0.x, aA0.y, aA0.z, aA0.w, aA1.x, aA1.y, aA1.z, aA1.w};
    float fB[8] = {aB0.x, aB0.y, aB0.z, aB0.w, aB1.x, aB1.y, aB1.z, aB1.w};
    bf16x8 ahA, alA, ahB, alB;
    cvt_hilo8(fA, &ahA, &alA);
    cvt_hilo8(fB, &ahB, &alB);
    bf16x8 vh0 = __builtin_bit_cast(bf16x8, bh0);
    bf16x8 vh1 = __builtin_bit_cast(bf16x8, bh1);
    bf16x8 vl0 = __builtin_bit_cast(bf16x8, bl0);
    bf16x8 vl1 = __builtin_bit_cast(bf16x8, bl1);
    // fp32-emulated: hi*hi + hi*lo + lo*hi (lo*lo ~2^-18, dropped)
    accA0 = __builtin_amdgcn_mfma_f32_32x32x16_bf16(ahA, vh0, accA0, 0, 0, 0);
    accA1 = __builtin_amdgcn_mfma_f32_32x32x16_bf16(ahA, vh1, accA1, 0, 0, 0);
    accB0 = __builtin_amdgcn_mfma_f32_32x32x16_bf16(ahB, vh0, accB0, 0, 0, 0);
    accB1 = __builtin_amdgcn_mfma_f32_32x32x16_bf16(ahB, vh1, accB1, 0, 0, 0);
    accA0 = __builtin_amdgcn_mfma_f32_32x32x16_bf16(ahA, vl0, accA0, 0, 0, 0);
    accA1 = __builtin_amdgcn_mfma_f32_32x32x16_bf16(ahA, vl1, accA1, 0, 0, 0);
    accB0 = __builtin_amdgcn_mfma_f32_32x32x16_bf16(ahB, vl0, accB0, 0, 0, 0);
    accB1 = __builtin_amdgcn_mfma_f32_32x32x16_bf16(ahB, vl1, accB1, 0, 0, 0);
    accA0 = __builtin_amdgcn_mfma_f32_32x32x16_bf16(alA, vh0, accA0, 0, 0, 0);
    accA1 = __builtin_amdgcn_mfma_f32_32x32x16_bf16(alA, vh1, accA1, 0, 0, 0);
    accB0 = __builtin_amdgcn_mfma_f32_32x32x16_bf16(alB, vh0, accB0, 0, 0, 0);
    accB1 = __builtin_amdgcn_mfma_f32_32x32x16_bf16(alB, vh1, accB1, 0, 0, 0);
  };

  ldxm(0, 0);
  ldw(0, 0); ldw(1, 1);

  for (int m = 0; m < NMAC; m += 2) {        // 2 macros/iter so slot ids stay literal
    if (m + 1 < NMAC) ldxm(m + 1, 1);        // next macro's bursts in flight over compute
    chunk(m * 2, 0, 0);  chunk(m * 2 + 1, 0, 1);
    if (m + 2 < NMAC) ldxm(m + 2, 0);
    chunk((m + 1) * 2, 1, 0);  chunk((m + 1) * 2 + 1, 1, 1);
  }

  // dump partials. C/D layout: expert col = lane&31, token row rr = (r&3)+8*(r>>2)+4*g
  {
    float* rp = &red[w][0];
#pragma unroll
    for (int r = 0; r < 16; ++r) {
      const int rr = (r & 3) + 8 * (r >> 2) + 4 * g;
      rp[rr * NEXP + row]             = accA0[r];   // 2-way bank alias -> free
      rp[rr * NEXP + 32 + row]        = accA1[r];
      rp[(32 + rr) * NEXP + row]      = accB0[r];
      rp[(32 + rr) * NEXP + 32 + row] = accB1[r];
    }
  }
  __syncthreads();

  // reduce 8 K-eighths + bias. thread owns f = tid + 512*j (bank tid%32, conflict-free;
  // expert index of f is tid&63 since 512*j is a multiple of 64)
  const float bias = b[tid & 63];
#pragma unroll
  for (int j = 0; j < 8; ++j) {
    const int f = tid + 512 * j;
    float s = red[0][f] + red[1][f] + red[2][f] + red[3][f]
            + red[4][f] + red[5][f] + red[6][f] + red[7][f] + bias;
    red[0][f] = s;                           // owner-exclusive, no race
  }
  __syncthreads();

  // top-2 + softmax: wave w handles tokens w*8 .. w*8+7, lane = expert
#pragma unroll
  for (int i = 0; i < 8; ++i) {
    const int tl = w * 8 + i;
    const float v = red[0][tl * NEXP + l];

    float m1 = v; int i1 = l;
#pragma unroll
    for (int off = 32; off > 0; off >>= 1) {
      float ov = __shfl_xor(m1, off, 64);
      int   oi = __shfl_xor(i1, off, 64);
      if (ov > m1 || (ov == m1 && oi < i1)) { m1 = ov; i1 = oi; }
    }
    float v2 = (l == i1) ? -__builtin_inff() : v;
    float m2 = v2; int i2 = l;
#pragma unroll
    for (int off = 32; off > 0; off >>= 1) {
      float ov = __shfl_xor(m2, off, 64);
      int   oi = __shfl_xor(i2, off, 64);
      if (ov > m2 || (ov == m2 && oi < i2)) { m2 = ov; i2 = oi; }
    }
    float e = __expf(v - m1);
#pragma unroll
    for (int off = 32; off > 0; off >>= 1) e += __shfl_xor(e, off, 64);

    if (l == 0) {
      const int t = t0 + tl;
      out[(size_t)t * 2 + 0] = (float)i1;
      out[(size_t)t * 2 + 1] = (float)i2;
      float inv = 1.0f / e;
      out[(size_t)TOKENS * 2 + (size_t)t * 2 + 0] = inv;
      out[(size_t)TOKENS * 2 + (size_t)t * 2 + 1] = __expf(m2 - m1) * inv;
    }
  }
}

extern "C" void kernel_launch(void* const* d_in, const int* in_sizes, int n_in,
                              void* d_out, int out_size, void* d_ws, size_t ws_size,
                              hipStream_t stream) {
  const float* x = (const float*)d_in[0];
  const float* W = (const float*)d_in[1];
  const float* b = (const float*)d_in[2];
  float* out = (float*)d_out;

  uint4* wh = (uint4*)d_ws;          // 32768 slots * 16B = 512 KB
  uint4* wl = wh + 32768;            // 512 KB

  void* args[] = { (void*)&x, (void*)&W, (void*)&wh, (void*)&wl, (void*)&b, (void*)&out };
  (void)hipLaunchCooperativeKernel((const void*)router_all, dim3(TOKENS / 64), dim3(512),
                                   args, 0, stream);
}

// Round 16
// 78.405 us; speedup vs baseline: 1.8286x; 1.8286x over previous
//
#include <hip/hip_runtime.h>
#include <hip/hip_bf16.h>
#include <cstdint>
#include <cstddef>

#define TOKENS 16384
#define DMODEL 4096
#define NEXP   64
#define NWAVE  8                      // waves per block = K-split within block
#define KSPAN  (DMODEL / NWAVE)       // 512 k per wave
#define NKC    (KSPAN / 16)           // 32 k16-chunks per wave
#define NMAC   (NKC / 4)              // 8 macro-iters (4 chunks = 256B/row burst)

typedef __attribute__((ext_vector_type(8)))  short bf16x8;   // 8 bf16 = 4 VGPRs
typedef __attribute__((ext_vector_type(16))) float f32x16;   // 32x32 acc

// 8 fp32 -> hi/lo bf16 fragments (RNE hi, exact fp32 residual -> lo; ~2^-17 rel)
__device__ __forceinline__ void cvt_hilo8(const float f[8], bf16x8* hi, bf16x8* lo) {
  union { __hip_bfloat16 b; unsigned short u; } cv;
  bf16x8 hv, lv;
#pragma unroll
  for (int j = 0; j < 8; ++j) {
    __hip_bfloat16 hb = __float2bfloat16(f[j]);
    cv.b = hb; hv[j] = (short)cv.u;
    float r = f[j] - __bfloat162float(hb);          // exact
    cv.b = __float2bfloat16(r); lv[j] = (short)cv.u;
  }
  *hi = hv; *lo = lv;
}

// ---------------- kernel 1: W -> 32x32x16 B-fragments, bf16 hi/lo (verified) ----------
// slot (kc*2+et)*64+l <- B[k=kc*16+(l>>5)*8+j][e=et*32+(l&31)] = W[e][k+j]
__global__ __launch_bounds__(256)
void prep_W(const float* __restrict__ W, uint4* __restrict__ wh, uint4* __restrict__ wl) {
  const int tid = blockIdx.x * 256 + threadIdx.x;   // 32768 threads total
  const int l  = tid & 63;
  const int et = (tid >> 6) & 1;
  const int kc = tid >> 7;                           // 0..255 (global k16-chunk)
  const int e  = et * 32 + (l & 31);
  const int k  = kc * 16 + (l >> 5) * 8;
  const float* src = W + (size_t)e * DMODEL + k;
  float f[8];
#pragma unroll
  for (int j = 0; j < 8; ++j) f[j] = src[j];
  bf16x8 hi, lo;
  cvt_hilo8(f, &hi, &lo);
  const int slot = (kc * 2 + et) * 64 + l;
  wh[slot] = __builtin_bit_cast(uint4, hi);
  wl[slot] = __builtin_bit_cast(uint4, lo);
}

// ---------------- kernel 2: tile-pair GEMM, 256B bursts + deep prefetch ----------------
// grid 256 x 512 thr (8 waves, 1 block/CU via 128KB LDS -> per-wave VGPR budget 256).
// Block = 64 tokens; wave w = K-eighth for tileA (t0..+31) and tileB (t0+32..+63); each
// W chunk read once from L2 for both tiles. Macro = 4 chunks: 256B/row bursts and
// issue-to-use distance ~1 macro of compute (~800cyc) to cover HBM latency.
__global__ __launch_bounds__(512, 2)
void gemm_topk(const float* __restrict__ x, const uint4* __restrict__ wh,
               const uint4* __restrict__ wl, const float* __restrict__ b,
               float* __restrict__ out) {
  __shared__ float red[NWAVE][64 * NEXP];   // 128 KB

  const int tid = threadIdx.x;
  const int l   = tid & 63;
  const int w   = tid >> 6;                 // wave id = K-eighth
  const int t0  = blockIdx.x * 64;
  const int row = l & 31, g = l >> 5;

  const float* xpA = x + (size_t)(t0 + row) * DMODEL + w * KSPAN + g * 8;
  const float* xpB = xpA + (size_t)32 * DMODEL;
  const uint4* whp = wh + (size_t)w * (NKC * 128) + l;   // 128 uint4 per k16-chunk
  const uint4* wlp = wl + (size_t)w * (NKC * 128) + l;

  f32x16 accA0, accA1, accB0, accB1;
#pragma unroll
  for (int i = 0; i < 16; ++i) { accA0[i] = 0.f; accA1[i] = 0.f; accB0[i] = 0.f; accB1[i] = 0.f; }

  // x: macro (4 chunks x 2 tiles = 16 float4) double-buffered (128 VGPR — free: LDS caps
  // occupancy at 8 waves/CU so budget is 256/wave); W: depth-2 chunk rotation (L2-hit).
  float4 xa[2][16];
  uint4  ph0[2], ph1[2], pl0[2], pl1[2];

  auto ldxm = [&](int mac, int s) {          // 256B/row bursts, tileA rows then tileB rows
#pragma unroll
    for (int c = 0; c < 4; ++c) {
      const float* xn = xpA + (size_t)(mac * 4 + c) * 16;
      xa[s][c * 2]     = *(const float4*)(xn);
      xa[s][c * 2 + 1] = *(const float4*)(xn + 4);
    }
#pragma unroll
    for (int c = 0; c < 4; ++c) {
      const float* xn = xpB + (size_t)(mac * 4 + c) * 16;
      xa[s][8 + c * 2]     = *(const float4*)(xn);
      xa[s][8 + c * 2 + 1] = *(const float4*)(xn + 4);
    }
  };
  auto ldw = [&](int kc, int s) {
    ph0[s] = whp[(size_t)kc * 128];  ph1[s] = whp[(size_t)kc * 128 + 64];
    pl0[s] = wlp[(size_t)kc * 128];  pl1[s] = wlp[(size_t)kc * 128 + 64];
  };

  auto chunk = [&](int kc, int xs, int c) {  // one W chunk -> both tiles (12 MFMA)
    const int ws = kc & 1;
    float4 aA0 = xa[xs][c * 2],     aA1 = xa[xs][c * 2 + 1];
    float4 aB0 = xa[xs][8 + c * 2], aB1 = xa[xs][8 + c * 2 + 1];
    uint4 bh0 = ph0[ws], bh1 = ph1[ws], bl0 = pl0[ws], bl1 = pl1[ws];
    if (kc + 2 < NKC) ldw(kc + 2, ws);       // same parity -> same slot, freed this chunk
    float fA[8] = {aA0.x, aA0.y, aA0.z, aA0.w, aA1.x, aA1.y, aA1.z, aA1.w};
    float fB[8] = {aB0.x, aB0.y, aB0.z, aB0.w, aB1.x, aB1.y, aB1.z, aB1.w};
    bf16x8 ahA, alA, ahB, alB;
    cvt_hilo8(fA, &ahA, &alA);
    cvt_hilo8(fB, &ahB, &alB);
    bf16x8 vh0 = __builtin_bit_cast(bf16x8, bh0);
    bf16x8 vh1 = __builtin_bit_cast(bf16x8, bh1);
    bf16x8 vl0 = __builtin_bit_cast(bf16x8, bl0);
    bf16x8 vl1 = __builtin_bit_cast(bf16x8, bl1);
    // fp32-emulated: hi*hi + hi*lo + lo*hi (lo*lo ~2^-18, dropped)
    accA0 = __builtin_amdgcn_mfma_f32_32x32x16_bf16(ahA, vh0, accA0, 0, 0, 0);
    accA1 = __builtin_amdgcn_mfma_f32_32x32x16_bf16(ahA, vh1, accA1, 0, 0, 0);
    accB0 = __builtin_amdgcn_mfma_f32_32x32x16_bf16(ahB, vh0, accB0, 0, 0, 0);
    accB1 = __builtin_amdgcn_mfma_f32_32x32x16_bf16(ahB, vh1, accB1, 0, 0, 0);
    accA0 = __builtin_amdgcn_mfma_f32_32x32x16_bf16(ahA, vl0, accA0, 0, 0, 0);
    accA1 = __builtin_amdgcn_mfma_f32_32x32x16_bf16(ahA, vl1, accA1, 0, 0, 0);
    accB0 = __builtin_amdgcn_mfma_f32_32x32x16_bf16(ahB, vl0, accB0, 0, 0, 0);
    accB1 = __builtin_amdgcn_mfma_f32_32x32x16_bf16(ahB, vl1, accB1, 0, 0, 0);
    accA0 = __builtin_amdgcn_mfma_f32_32x32x16_bf16(alA, vh0, accA0, 0, 0, 0);
    accA1 = __builtin_amdgcn_mfma_f32_32x32x16_bf16(alA, vh1, accA1, 0, 0, 0);
    accB0 = __builtin_amdgcn_mfma_f32_32x32x16_bf16(alB, vh0, accB0, 0, 0, 0);
    accB1 = __builtin_amdgcn_mfma_f32_32x32x16_bf16(alB, vh1, accB1, 0, 0, 0);
  };

  ldxm(0, 0);
  ldw(0, 0); ldw(1, 1);

  for (int m = 0; m < NMAC; m += 2) {        // 2 macros/iter so slot ids stay literal
    if (m + 1 < NMAC) ldxm(m + 1, 1);        // next macro's bursts in flight over compute
#pragma unroll
    for (int c = 0; c < 4; ++c) chunk(m * 4 + c, 0, c);
    if (m + 2 < NMAC) ldxm(m + 2, 0);
#pragma unroll
    for (int c = 0; c < 4; ++c) chunk((m + 1) * 4 + c, 1, c);
  }

  // dump partials. C/D layout: expert col = lane&31, token row rr = (r&3)+8*(r>>2)+4*g
  {
    float* rp = &red[w][0];
#pragma unroll
    for (int r = 0; r < 16; ++r) {
      const int rr = (r & 3) + 8 * (r >> 2) + 4 * g;
      rp[rr * NEXP + row]             = accA0[r];   // 2-way bank alias -> free
      rp[rr * NEXP + 32 + row]        = accA1[r];
      rp[(32 + rr) * NEXP + row]      = accB0[r];
      rp[(32 + rr) * NEXP + 32 + row] = accB1[r];
    }
  }
  __syncthreads();

  // reduce 8 K-eighths + bias. thread owns f = tid + 512*j (bank tid%32, conflict-free;
  // expert index of f is tid&63 since 512*j is a multiple of 64)
  const float bias = b[tid & 63];
#pragma unroll
  for (int j = 0; j < 8; ++j) {
    const int f = tid + 512 * j;
    float s = red[0][f] + red[1][f] + red[2][f] + red[3][f]
            + red[4][f] + red[5][f] + red[6][f] + red[7][f] + bias;
    red[0][f] = s;                           // owner-exclusive, no race
  }
  __syncthreads();

  // top-2 + softmax: wave w handles tokens w*8 .. w*8+7, lane = expert
#pragma unroll
  for (int i = 0; i < 8; ++i) {
    const int tl = w * 8 + i;
    const float v = red[0][tl * NEXP + l];

    float m1 = v; int i1 = l;
#pragma unroll
    for (int off = 32; off > 0; off >>= 1) {
      float ov = __shfl_xor(m1, off, 64);
      int   oi = __shfl_xor(i1, off, 64);
      if (ov > m1 || (ov == m1 && oi < i1)) { m1 = ov; i1 = oi; }
    }
    float v2 = (l == i1) ? -__builtin_inff() : v;
    float m2 = v2; int i2 = l;
#pragma unroll
    for (int off = 32; off > 0; off >>= 1) {
      float ov = __shfl_xor(m2, off, 64);
      int   oi = __shfl_xor(i2, off, 64);
      if (ov > m2 || (ov == m2 && oi < i2)) { m2 = ov; i2 = oi; }
    }
    float e = __expf(v - m1);
#pragma unroll
    for (int off = 32; off > 0; off >>= 1) e += __shfl_xor(e, off, 64);

    if (l == 0) {
      const int t = t0 + tl;
      out[(size_t)t * 2 + 0] = (float)i1;
      out[(size_t)t * 2 + 1] = (float)i2;
      float inv = 1.0f / e;
      out[(size_t)TOKENS * 2 + (size_t)t * 2 + 0] = inv;
      out[(size_t)TOKENS * 2 + (size_t)t * 2 + 1] = __expf(m2 - m1) * inv;
    }
  }
}

extern "C" void kernel_launch(void* const* d_in, const int* in_sizes, int n_in,
                              void* d_out, int out_size, void* d_ws, size_t ws_size,
                              hipStream_t stream) {
  const float* x = (const float*)d_in[0];
  const float* W = (const float*)d_in[1];
  const float* b = (const float*)d_in[2];
  float* out = (float*)d_out;

  uint4* wh = (uint4*)d_ws;          // 32768 slots * 16B = 512 KB
  uint4* wl = wh + 32768;            // 512 KB

  hipLaunchKernelGGL(prep_W,    dim3(128),         dim3(256), 0, stream, W, wh, wl);
  hipLaunchKernelGGL(gemm_topk, dim3(TOKENS / 64), dim3(512), 0, stream, x, wh, wl, b, out);
}

// Round 17
// 75.622 us; speedup vs baseline: 1.8959x; 1.0368x over previous
//
#include <hip/hip_runtime.h>
#include <hip/hip_bf16.h>
#include <cstdint>
#include <cstddef>

#define TOKENS 16384
#define DMODEL 4096
#define NEXP   64
#define NWAVE  8                      // waves per block = K-split within block
#define KSPAN  (DMODEL / NWAVE)       // 512 k per wave
#define NKC    (KSPAN / 16)           // 32 k16-chunks per wave
#define NMAC   (NKC / 2)              // 16 macro-iters (2 chunks = 128B/row burst)

typedef __attribute__((ext_vector_type(8)))  short bf16x8;   // 8 bf16 = 4 VGPRs
typedef __attribute__((ext_vector_type(16))) float f32x16;   // 32x32 acc

// 8 fp32 -> hi/lo bf16 fragments (RNE hi, exact fp32 residual -> lo; ~2^-17 rel)
__device__ __forceinline__ void cvt_hilo8(const float f[8], bf16x8* hi, bf16x8* lo) {
  union { __hip_bfloat16 b; unsigned short u; } cv;
  bf16x8 hv, lv;
#pragma unroll
  for (int j = 0; j < 8; ++j) {
    __hip_bfloat16 hb = __float2bfloat16(f[j]);
    cv.b = hb; hv[j] = (short)cv.u;
    float r = f[j] - __bfloat162float(hb);          // exact
    cv.b = __float2bfloat16(r); lv[j] = (short)cv.u;
  }
  *hi = hv; *lo = lv;
}

// ---------------- kernel 1: W -> 32x32x16 B-fragments, bf16 hi/lo (verified) ----------
// slot (kc*2+et)*64+l <- B[k=kc*16+(l>>5)*8+j][e=et*32+(l&31)] = W[e][k+j]
__global__ __launch_bounds__(256)
void prep_W(const float* __restrict__ W, uint4* __restrict__ wh, uint4* __restrict__ wl) {
  const int tid = blockIdx.x * 256 + threadIdx.x;   // 32768 threads total
  const int l  = tid & 63;
  const int et = (tid >> 6) & 1;
  const int kc = tid >> 7;                           // 0..255 (global k16-chunk)
  const int e  = et * 32 + (l & 31);
  const int k  = kc * 16 + (l >> 5) * 8;
  const float* src = W + (size_t)e * DMODEL + k;
  float f[8];
#pragma unroll
  for (int j = 0; j < 8; ++j) f[j] = src[j];
  bf16x8 hi, lo;
  cvt_hilo8(f, &hi, &lo);
  const int slot = (kc * 2 + et) * 64 + l;
  wh[slot] = __builtin_bit_cast(uint4, hi);
  wl[slot] = __builtin_bit_cast(uint4, lo);
}

// ---------------- kernel 2: tile-pair GEMM (W read once per 64 tokens) + epilogue ------
// grid 256 x 512 thr (8 waves, 1 block/CU, 2 waves/SIMD). Block = 64 tokens; wave w =
// K-eighth w for tileA (t0..+31) AND tileB (t0+32..+63) -- each W chunk loaded from L2
// once and MFMA'd against both tiles (halves W L2 traffic vs single-tile).
__global__ __launch_bounds__(512, 2)
void gemm_topk(const float* __restrict__ x, const uint4* __restrict__ wh,
               const uint4* __restrict__ wl, const float* __restrict__ b,
               float* __restrict__ out) {
  __shared__ float red[NWAVE][64 * NEXP];   // 128 KB

  const int tid = threadIdx.x;
  const int l   = tid & 63;
  const int w   = tid >> 6;                 // wave id = K-eighth
  const int t0  = blockIdx.x * 64;
  const int row = l & 31, g = l >> 5;

  const float* xpA = x + (size_t)(t0 + row) * DMODEL + w * KSPAN + g * 8;
  const float* xpB = xpA + (size_t)32 * DMODEL;
  const uint4* whp = wh + (size_t)w * (NKC * 128) + l;   // 128 uint4 per k16-chunk
  const uint4* wlp = wl + (size_t)w * (NKC * 128) + l;

  f32x16 accA0, accA1, accB0, accB1;
#pragma unroll
  for (int i = 0; i < 16; ++i) { accA0[i] = 0.f; accA1[i] = 0.f; accB0[i] = 0.f; accB1[i] = 0.f; }

  // x: macro (2 chunks x 2 tiles = 8 float4) double-buffered; W: depth-2 chunk rotation.
  float4 xa[2][8];
  uint4  ph0[2], ph1[2], pl0[2], pl1[2];

  auto ldxm = [&](int mac, int s) {          // 128B/row bursts, tileA rows then tileB rows
#pragma unroll
    for (int c = 0; c < 2; ++c) {
      const float* xn = xpA + (size_t)(mac * 2 + c) * 16;
      xa[s][c * 2]     = *(const float4*)(xn);
      xa[s][c * 2 + 1] = *(const float4*)(xn + 4);
    }
#pragma unroll
    for (int c = 0; c < 2; ++c) {
      const float* xn = xpB + (size_t)(mac * 2 + c) * 16;
      xa[s][4 + c * 2]     = *(const float4*)(xn);
      xa[s][4 + c * 2 + 1] = *(const float4*)(xn + 4);
    }
  };
  auto ldw = [&](int kc, int s) {
    ph0[s] = whp[(size_t)kc * 128];  ph1[s] = whp[(size_t)kc * 128 + 64];
    pl0[s] = wlp[(size_t)kc * 128];  pl1[s] = wlp[(size_t)kc * 128 + 64];
  };

  auto chunk = [&](int kc, int xs, int c) {  // one W chunk -> both tiles (12 MFMA)
    const int ws = kc & 1;
    float4 aA0 = xa[xs][c * 2],     aA1 = xa[xs][c * 2 + 1];
    float4 aB0 = xa[xs][4 + c * 2], aB1 = xa[xs][4 + c * 2 + 1];
    uint4 bh0 = ph0[ws], bh1 = ph1[ws], bl0 = pl0[ws], bl1 = pl1[ws];
    if (kc + 2 < NKC) ldw(kc + 2, ws);       // same parity -> same slot, freed this chunk
    float fA[8] = {aA0.x, aA0.y, aA0.z, aA0.w, aA1.x, aA1.y, aA1.z, aA1.w};
    float fB[8] = {aB0.x, aB0.y, aB0.z, aB0.w, aB1.x, aB1.y, aB1.z, aB1.w};
    bf16x8 ahA, alA, ahB, alB;
    cvt_hilo8(fA, &ahA, &alA);
    cvt_hilo8(fB, &ahB, &alB);
    bf16x8 vh0 = __builtin_bit_cast(bf16x8, bh0);
    bf16x8 vh1 = __builtin_bit_cast(bf16x8, bh1);
    bf16x8 vl0 = __builtin_bit_cast(bf16x8, bl0);
    bf16x8 vl1 = __builtin_bit_cast(bf16x8, bl1);
    // fp32-emulated: hi*hi + hi*lo + lo*hi (lo*lo ~2^-18, dropped)
    accA0 = __builtin_amdgcn_mfma_f32_32x32x16_bf16(ahA, vh0, accA0, 0, 0, 0);
    accA1 = __builtin_amdgcn_mfma_f32_32x32x16_bf16(ahA, vh1, accA1, 0, 0, 0);
    accB0 = __builtin_amdgcn_mfma_f32_32x32x16_bf16(ahB, vh0, accB0, 0, 0, 0);
    accB1 = __builtin_amdgcn_mfma_f32_32x32x16_bf16(ahB, vh1, accB1, 0, 0, 0);
    accA0 = __builtin_amdgcn_mfma_f32_32x32x16_bf16(ahA, vl0, accA0, 0, 0, 0);
    accA1 = __builtin_amdgcn_mfma_f32_32x32x16_bf16(ahA, vl1, accA1, 0, 0, 0);
    accB0 = __builtin_amdgcn_mfma_f32_32x32x16_bf16(ahB, vl0, accB0, 0, 0, 0);
    accB1 = __builtin_amdgcn_mfma_f32_32x32x16_bf16(ahB, vl1, accB1, 0, 0, 0);
    accA0 = __builtin_amdgcn_mfma_f32_32x32x16_bf16(alA, vh0, accA0, 0, 0, 0);
    accA1 = __builtin_amdgcn_mfma_f32_32x32x16_bf16(alA, vh1, accA1, 0, 0, 0);
    accB0 = __builtin_amdgcn_mfma_f32_32x32x16_bf16(alB, vh0, accB0, 0, 0, 0);
    accB1 = __builtin_amdgcn_mfma_f32_32x32x16_bf16(alB, vh1, accB1, 0, 0, 0);
  };

  ldxm(0, 0);
  ldw(0, 0); ldw(1, 1);

  for (int m = 0; m < NMAC; m += 2) {        // 2 macros/iter so slot ids stay literal
    if (m + 1 < NMAC) ldxm(m + 1, 1);        // next macro's bursts in flight over compute
    chunk(m * 2, 0, 0);  chunk(m * 2 + 1, 0, 1);
    if (m + 2 < NMAC) ldxm(m + 2, 0);
    chunk((m + 1) * 2, 1, 0);  chunk((m + 1) * 2 + 1, 1, 1);
  }

  // dump partials. C/D layout: expert col = lane&31, token row rr = (r&3)+8*(r>>2)+4*g
  {
    float* rp = &red[w][0];
#pragma unroll
    for (int r = 0; r < 16; ++r) {
      const int rr = (r & 3) + 8 * (r >> 2) + 4 * g;
      rp[rr * NEXP + row]             = accA0[r];   // 2-way bank alias -> free
      rp[rr * NEXP + 32 + row]        = accA1[r];
      rp[(32 + rr) * NEXP + row]      = accB0[r];
      rp[(32 + rr) * NEXP + 32 + row] = accB1[r];
    }
  }
  __syncthreads();

  // reduce 8 K-eighths + bias. thread owns f = tid + 512*j (bank tid%32, conflict-free;
  // expert index of f is tid&63 since 512*j is a multiple of 64)
  const float bias = b[tid & 63];
#pragma unroll
  for (int j = 0; j < 8; ++j) {
    const int f = tid + 512 * j;
    float s = red[0][f] + red[1][f] + red[2][f] + red[3][f]
            + red[4][f] + red[5][f] + red[6][f] + red[7][f] + bias;
    red[0][f] = s;                           // owner-exclusive, no race
  }
  __syncthreads();

  // top-2 + softmax: wave w handles tokens w*8 .. w*8+7, lane = expert
#pragma unroll
  for (int i = 0; i < 8; ++i) {
    const int tl = w * 8 + i;
    const float v = red[0][tl * NEXP + l];

    float m1 = v; int i1 = l;
#pragma unroll
    for (int off = 32; off > 0; off >>= 1) {
      float ov = __shfl_xor(m1, off, 64);
      int   oi = __shfl_xor(i1, off, 64);
      if (ov > m1 || (ov == m1 && oi < i1)) { m1 = ov; i1 = oi; }
    }
    float v2 = (l == i1) ? -__builtin_inff() : v;
    float m2 = v2; int i2 = l;
#pragma unroll
    for (int off = 32; off > 0; off >>= 1) {
      float ov = __shfl_xor(m2, off, 64);
      int   oi = __shfl_xor(i2, off, 64);
      if (ov > m2 || (ov == m2 && oi < i2)) { m2 = ov; i2 = oi; }
    }
    float e = __expf(v - m1);
#pragma unroll
    for (int off = 32; off > 0; off >>= 1) e += __shfl_xor(e, off, 64);

    if (l == 0) {
      const int t = t0 + tl;
      out[(size_t)t * 2 + 0] = (float)i1;
      out[(size_t)t * 2 + 1] = (float)i2;
      float inv = 1.0f / e;
      out[(size_t)TOKENS * 2 + (size_t)t * 2 + 0] = inv;
      out[(size_t)TOKENS * 2 + (size_t)t * 2 + 1] = __expf(m2 - m1) * inv;
    }
  }
}

extern "C" void kernel_launch(void* const* d_in, const int* in_sizes, int n_in,
                              void* d_out, int out_size, void* d_ws, size_t ws_size,
                              hipStream_t stream) {
  const float* x = (const float*)d_in[0];
  const float* W = (const float*)d_in[1];
  const float* b = (const float*)d_in[2];
  float* out = (float*)d_out;

  uint4* wh = (uint4*)d_ws;          // 32768 slots * 16B = 512 KB
  uint4* wl = wh + 32768;            // 512 KB

  hipLaunchKernelGGL(prep_W,    dim3(128),         dim3(256), 0, stream, W, wh, wl);
  hipLaunchKernelGGL(gemm_topk, dim3(TOKENS / 64), dim3(512), 0, stream, x, wh, wl, b, out);
}